// Round 4
// baseline (678.947 us; speedup 1.0000x reference)
//
#include <hip/hip_runtime.h>
#include <math.h>

#define IMG_H 2048
#define IMG_W 2048
#define TILE  64
#define STR   72   // LDS row stride

// Hypothesis V1: np reference computes each conv in float64 (exact: weights
// are powers of two / +-1 / +-2, products exact, 9-term fp64 sum exact to
// 2^-53) and casts to float32 at each stage boundary; magnitude in plain
// fp32 numpy ops (rn mul, rn mul, rn add, correctly-rounded sqrt). This is
// order-free and conv/correlation-invariant, so it covers a whole class of
// plausible numpy twins (astype-per-stage tap loops, scipy.ndimage, einsum
// in fp64). NMS compare in fp32 on those bits.
__global__ __launch_bounds__(256) void edge_kernel(const float* __restrict__ img,
                                                   float* __restrict__ out) {
    __shared__ float buf_a[70 * STR];  // input tile, later reused for edges
    __shared__ float buf_s[68 * STR];  // smoothed tile (fp32 per-stage rounding)

    const int tid = threadIdx.x;
    const int bx = blockIdx.x, by = blockIdx.y, n = blockIdx.z;
    const int x0 = bx * TILE - 3;
    const int y0 = by * TILE - 3;
    const float* __restrict__ imgN = img + (size_t)n * (IMG_H * IMG_W);
    float* __restrict__ outN = out + (size_t)n * (IMG_H * IMG_W);

    // ---- stage 1: load 70x70 input tile, zero outside image (SAME pad) ----
    for (int i = tid; i < 70 * 70; i += 256) {
        int ly = i / 70;
        int lx = i - ly * 70;
        int gy = y0 + ly, gx = x0 + lx;
        float v = 0.0f;
        if ((unsigned)gy < IMG_H && (unsigned)gx < IMG_W)
            v = imgN[gy * IMG_W + gx];
        buf_a[ly * STR + lx] = v;
    }
    __syncthreads();

    // ---- stage 2: Gaussian 3x3, exact fp64 accumulate -> round to fp32 ----
    for (int i = tid; i < 68 * 68; i += 256) {
        int ly = i / 68;
        int lx = i - ly * 68;
        int gy = y0 + 1 + ly, gx = x0 + 1 + lx;
        float vf = 0.0f;
        if ((unsigned)gy < IMG_H && (unsigned)gx < IMG_W) {
            const float* c = &buf_a[(ly + 1) * STR + (lx + 1)];
            double v = 0.0625 * (double)c[-STR - 1]
                     + 0.125  * (double)c[-STR]
                     + 0.0625 * (double)c[-STR + 1]
                     + 0.125  * (double)c[-1]
                     + 0.25   * (double)c[0]
                     + 0.125  * (double)c[1]
                     + 0.0625 * (double)c[STR - 1]
                     + 0.125  * (double)c[STR]
                     + 0.0625 * (double)c[STR + 1];
            vf = (float)v;   // single rounding: per-stage fp32 boundary
        }
        buf_s[ly * STR + lx] = vf;
    }
    __syncthreads();

    // ---- stage 3: Sobel in exact fp64 -> round gx,gy to fp32, fp32 magnitude ----
    for (int i = tid; i < 66 * 66; i += 256) {
        int ly = i / 66;
        int lx = i - ly * 66;
        int gy = y0 + 2 + ly, gx = x0 + 2 + lx;
        float v = 0.0f;
        if ((unsigned)gy < IMG_H && (unsigned)gx < IMG_W) {
            const float* c = &buf_s[(ly + 1) * STR + (lx + 1)];
            double a = (double)c[-STR - 1], b = (double)c[-STR], d = (double)c[-STR + 1];
            double e = (double)c[-1],                            f = (double)c[1];
            double g = (double)c[STR - 1],  h = (double)c[STR],  p = (double)c[STR + 1];
            double gxd = (d - a) + 2.0 * (f - e) + (p - g);
            double gyd = (g - a) + 2.0 * (h - b) + (p - d);
            float gxf = (float)gxd;          // per-stage fp32 rounding of gx
            float gyf = (float)gyd;          // and gy
            float m2 = __fadd_rn(__fmul_rn(gxf, gxf), __fmul_rn(gyf, gyf));
            v = (float)sqrt((double)m2);     // correctly-rounded fp32 sqrt
        }
        buf_a[ly * STR + lx] = v;
    }
    __syncthreads();

    // ---- stage 4: NMS (interior only, exact fp32 compare) + store ----
    for (int i = tid; i < 64 * 64; i += 256) {
        int ly = i >> 6;
        int lx = i & 63;
        int gy = by * TILE + ly, gx = bx * TILE + lx;
        const float* c = &buf_a[(ly + 1) * STR + (lx + 1)];
        float cen = c[0];
        float r = cen;
        if (gy > 0 && gy < IMG_H - 1 && gx > 0 && gx < IMG_W - 1) {
            float m = fmaxf(fmaxf(fmaxf(c[-STR - 1], c[-STR]), fmaxf(c[-STR + 1], c[-1])),
                            fmaxf(fmaxf(c[1], c[STR - 1]), fmaxf(c[STR], c[STR + 1])));
            r = (cen < m) ? 0.0f : cen;
        }
        outN[gy * IMG_W + gx] = r;
    }
}

extern "C" void kernel_launch(void* const* d_in, const int* in_sizes, int n_in,
                              void* d_out, int out_size, void* d_ws, size_t ws_size,
                              hipStream_t stream) {
    const float* img = (const float*)d_in[0];
    float* out = (float*)d_out;
    dim3 grid(IMG_W / TILE, IMG_H / TILE, 16);
    edge_kernel<<<grid, dim3(256), 0, stream>>>(img, out);
}